// Round 13
// baseline (49822.668 us; speedup 1.0000x reference)
//
#include <hip/hip_runtime.h>
#include <stdint.h>

#define S_LEN 8192
#define E_DIM 100
#define H_DIM 768
#define NTAG 7
#define G4 3072            // 4*H
#define NBLK 96            // blocks per direction
#define NCHUNK 128
#define POLL_LIMIT 200000

typedef unsigned short u16;
typedef __attribute__((ext_vector_type(4))) float f4v;

// input dtype flag (written by detect every call)
__device__ int g_isbf16;

__device__ __forceinline__ u16 f2bf(float f) {
    union { float f; unsigned u; } v; v.f = f;
    unsigned b = v.u;
    unsigned r = (b + 0x7FFFu + ((b >> 16) & 1u)) >> 16;   // RN
    return (u16)r;
}
__device__ __forceinline__ float bf2f(u16 u) {
    union { unsigned u; float f; } v; v.u = ((unsigned)u) << 16;
    return v.f;
}
__device__ __forceinline__ float getv(const void* p, size_t i, int isbf) {
    return isbf ? bf2f(((const u16*)p)[i]) : ((const float*)p)[i];
}
__device__ __forceinline__ float sigm(float x) { return 1.0f / (1.0f + __expf(-x)); }

// ---------------------------------------------------------------------------
// Dtype probe (256 B read, safe under either dtype).
// ---------------------------------------------------------------------------
__global__ void detect(const void* x) {
    __shared__ int cnt;
    if (threadIdx.x == 0) cnt = 0;
    __syncthreads();
    unsigned v = ((const u16*)x)[2 * threadIdx.x];
    int e = (v >> 7) & 0xFF;
    if (e >= 110 && e <= 132) atomicAdd(&cnt, 1);
    __syncthreads();
    if (threadIdx.x == 0) g_isbf16 = (cnt >= 100) ? 1 : 0;
}

// ---------------------------------------------------------------------------
// Prep: zero flags, fold biases, seed h row 0 (bf16) + c0 (fp32).
// ---------------------------------------------------------------------------
__global__ void prep(const void* bihf, const void* bhhf,
                     const void* bihb, const void* bhhb,
                     const void* h0, const void* c0,
                     u16* __restrict__ hf, u16* __restrict__ hb,
                     float* __restrict__ cst, float* __restrict__ bias,
                     unsigned* __restrict__ flags) {
    const int isbf = g_isbf16;
    int i = blockIdx.x * blockDim.x + threadIdx.x;   // 0..3071
    if (i < 256) flags[i] = 0;
    if (i < G4) {
        bias[i]      = getv(bihf, i, isbf) + getv(bhhf, i, isbf);
        bias[G4 + i] = getv(bihb, i, isbf) + getv(bhhb, i, isbf);
    }
    if (i < H_DIM) {
        hf[i] = f2bf(getv(h0, i, isbf));
        hb[i] = f2bf(getv(h0, H_DIM + i, isbf));
    }
    if (i < 2 * H_DIM) cst[i] = getv(c0, i, isbf);
}

// ---------------------------------------------------------------------------
// Persistent bidirectional LSTM. 192 blocks (96/dir, <=256 CUs -> co-resident),
// 256 thr: 32 gate rows (4 gates x 8 units) x 8 col-segments. Each thread holds
// 96 W_hh + 13 W_ih fp32 weights in REGISTERS (immune to acquire-invalidates).
// h_t staged to LDS (stride 100 -> seg slices on disjoint banks). x-term
// computed pre-wait. Handoff: bf16 h + per-block monotonic flag (release /
// relaxed poll + acquire fence). Bounded spin + bail latch: always terminates.
// ---------------------------------------------------------------------------
__global__ __launch_bounds__(256, 1) void lstm_persist(
        const void* x,
        const void* wihf, const void* whhf,
        const void* wihb, const void* whhb,
        u16* __restrict__ hfseq, u16* __restrict__ hbseq,
        float* __restrict__ cstate, const float* __restrict__ biasv,
        unsigned* __restrict__ flags, int* __restrict__ bail) {
    const int isbf = g_isbf16;
    const int bid = blockIdx.x;
    const int dir = (bid >= NBLK) ? 1 : 0;
    const int blk = bid - dir * NBLK;
    const int tid = threadIdx.x;
    const int wave = tid >> 6, lane = tid & 63;
    const int seg = tid & 7;            // col segment
    const int row = tid >> 3;           // 0..31 local gate rows
    const int gamma = row & 3;          // gate: 0=i 1=f 2=g 3=o
    const int uloc = row >> 2;          // 0..7
    const int u = blk * 8 + uloc;
    const size_t grow = (size_t)(gamma * H_DIM + u);       // row in (3072, .)
    u16* hseq = dir ? hbseq : hfseq;
    unsigned* myflags = flags + dir * 128;
    const void* Wih = dir ? wihb : wihf;
    const void* Whh = dir ? whhb : whhf;

    __shared__ float sh[800];           // h_t fp32, layout (k/96)*100 + k%96

    // ---- preload weights into registers (one-time) ----
    float whh[96], wih[13];
    if (isbf) {
        const unsigned* p = (const unsigned*)((const u16*)Whh + grow * H_DIM + seg * 96);
        #pragma unroll
        for (int i = 0; i < 48; ++i) {
            unsigned q = p[i];
            whh[2 * i] = bf2f((u16)q); whh[2 * i + 1] = bf2f((u16)(q >> 16));
        }
        const unsigned* px = (const unsigned*)((const u16*)Wih + grow * E_DIM + seg * 12);
        #pragma unroll
        for (int i = 0; i < 6; ++i) {
            unsigned q = px[i];
            wih[2 * i] = bf2f((u16)q); wih[2 * i + 1] = bf2f((u16)(q >> 16));
        }
        wih[12] = (seg < 4) ? bf2f(((const u16*)Wih)[grow * E_DIM + 96 + seg]) : 0.f;
    } else {
        const float* p = (const float*)Whh + grow * H_DIM + seg * 96;
        #pragma unroll
        for (int i = 0; i < 96; ++i) whh[i] = p[i];
        const float* px = (const float*)Wih + grow * E_DIM + seg * 12;
        #pragma unroll
        for (int i = 0; i < 12; ++i) wih[i] = px[i];
        wih[12] = (seg < 4) ? ((const float*)Wih)[grow * E_DIM + 96 + seg] : 0.f;
    }
    const float bias_r = biasv[dir * G4 + grow];
    const int uhalf = blk * 8 + wave * 2 + (lane >> 5);    // unit of this half-wave
    float cst = cstate[dir * H_DIM + uhalf];

    for (int t = 0; t < S_LEN; ++t) {
        const int sx = dir ? (S_LEN - 1 - t) : t;

        // ---- x-projection (independent of other blocks; pre-wait) ----
        float ax = 0.f;
        if (isbf) {
            const unsigned* xr = (const unsigned*)((const u16*)x + (size_t)sx * E_DIM + seg * 12);
            #pragma unroll
            for (int i = 0; i < 6; ++i) {
                unsigned q = xr[i];
                ax += wih[2 * i] * bf2f((u16)q) + wih[2 * i + 1] * bf2f((u16)(q >> 16));
            }
            if (seg < 4) ax += wih[12] * bf2f(((const u16*)x)[(size_t)sx * E_DIM + 96 + seg]);
        } else {
            const float* xr = (const float*)x + (size_t)sx * E_DIM + seg * 12;
            #pragma unroll
            for (int i = 0; i < 12; ++i) ax += wih[i] * xr[i];
            if (seg < 4) ax += wih[12] * ((const float*)x)[(size_t)sx * E_DIM + 96 + seg];
        }

        // ---- wait for h_t from all 96 blocks of this direction ----
        if (t > 0) {
            if (wave == 0) {
                if (!__hip_atomic_load(bail, __ATOMIC_RELAXED, __HIP_MEMORY_SCOPE_AGENT)) {
                    const unsigned tgt = (unsigned)t;
                    int polls = 0;
                    for (;;) {
                        unsigned v0 = __hip_atomic_load(&myflags[lane], __ATOMIC_RELAXED,
                                                        __HIP_MEMORY_SCOPE_AGENT);
                        unsigned v1 = (lane < 32)
                            ? __hip_atomic_load(&myflags[64 + lane], __ATOMIC_RELAXED,
                                                __HIP_MEMORY_SCOPE_AGENT) : tgt;
                        if (__all((v0 >= tgt) && (v1 >= tgt))) break;
                        if (__hip_atomic_load(bail, __ATOMIC_RELAXED,
                                              __HIP_MEMORY_SCOPE_AGENT)) break;
                        if (++polls > POLL_LIMIT) {
                            if (lane == 0)
                                __hip_atomic_store(bail, 1, __ATOMIC_RELAXED,
                                                   __HIP_MEMORY_SCOPE_AGENT);
                            break;
                        }
                        __builtin_amdgcn_s_sleep(2);
                    }
                }
                __builtin_amdgcn_fence(__ATOMIC_ACQUIRE, "agent");
            }
            __syncthreads();                             // bar A
        }

        // ---- stage h_t -> LDS fp32 (bank-decorrelated) ----
        const u16* hrow = hseq + (size_t)t * H_DIM;
        for (int k = tid; k < H_DIM; k += 256)
            sh[(k / 96) * 100 + (k % 96)] = bf2f(hrow[k]);
        __syncthreads();                                 // bar B

        // ---- h-projection: 96 FMA from LDS ----
        const float* hs = sh + seg * 100;
        float a0 = 0.f, a1 = 0.f, a2 = 0.f, a3 = 0.f;
        #pragma unroll
        for (int i = 0; i < 24; ++i) {
            f4v hv = *(const f4v*)(hs + 4 * i);
            a0 += whh[4 * i]     * hv.x;
            a1 += whh[4 * i + 1] * hv.y;
            a2 += whh[4 * i + 2] * hv.z;
            a3 += whh[4 * i + 3] * hv.w;
        }
        float acc = ax + (a0 + a1) + (a2 + a3);
        acc += __shfl_xor(acc, 1);
        acc += __shfl_xor(acc, 2);
        acc += __shfl_xor(acc, 4);       // 8-lane row sum
        float g = acc + bias_r;

        const int base = lane & 32;      // 4 gates of this half-wave's unit
        float gi = __shfl(g, base + 0);
        float gf = __shfl(g, base + 8);
        float gg = __shfl(g, base + 16);
        float go = __shfl(g, base + 24);
        float ii = sigm(gi), ff = sigm(gf), gt = tanhf(gg), oo = sigm(go);
        float c = ff * cst + ii * gt;
        cst = c;
        float h = oo * tanhf(c);
        if ((lane & 31) == 0)
            hseq[(size_t)(t + 1) * H_DIM + uhalf] = f2bf(h);

        __syncthreads();                                 // bar C: h stores drained
        if (tid == 0)
            __hip_atomic_store(&myflags[blk], (unsigned)(t + 1), __ATOMIC_RELEASE,
                               __HIP_MEMORY_SCOPE_AGENT);
    }
}

// ---------------------------------------------------------------------------
// feats[s][j] = [hf[s], hb[s]] . w_tag[j] + b_tag[j]; one wave per s.
// ---------------------------------------------------------------------------
__global__ __launch_bounds__(256) void feats_kernel(const u16* __restrict__ hfseq,
                                                    const u16* __restrict__ hbseq,
                                                    const void* w_tag, const void* b_tag,
                                                    float* __restrict__ feats) {
    const int isbf = g_isbf16;
    const int wave = threadIdx.x >> 6, lane = threadIdx.x & 63;
    const int s = blockIdx.x * 4 + wave;
    if (s >= S_LEN) return;
    const u16* hf = hfseq + (size_t)(s + 1) * H_DIM;
    const u16* hb = hbseq + (size_t)(S_LEN - s) * H_DIM;
    float hv[12], hbv[12];
    #pragma unroll
    for (int i = 0; i < 12; ++i) {
        hv[i]  = bf2f(hf[lane + 64 * i]);
        hbv[i] = bf2f(hb[lane + 64 * i]);
    }
    float myf = 0.f;
    for (int j = 0; j < NTAG; ++j) {
        const size_t wr = (size_t)j * (2 * H_DIM);
        float d = 0.f;
        #pragma unroll
        for (int i = 0; i < 12; ++i)
            d += hv[i] * getv(w_tag, wr + lane + 64 * i, isbf)
               + hbv[i] * getv(w_tag, wr + H_DIM + lane + 64 * i, isbf);
        #pragma unroll
        for (int m = 1; m < 64; m <<= 1) d += __shfl_xor(d, m);
        if (lane == j) myf = d + getv(b_tag, j, isbf);
    }
    if (lane < NTAG) feats[(size_t)s * NTAG + lane] = myf;
}

// ---------------------------------------------------------------------------
// CRF parallel scan (log-semiring 7x7 product is associative).
// ---------------------------------------------------------------------------
__global__ void crf_chunks(const void* trans,
                           const float* __restrict__ feats,
                           float* __restrict__ cmats) {
    const int isbf = g_isbf16;
    const int c = blockIdx.x;
    const int lane = threadIdx.x;
    const bool act = lane < 49;
    const int i = act ? (lane / 7) : 0;
    const int j = lane % 7;
    float tc[7];
    #pragma unroll
    for (int k = 0; k < 7; ++k) tc[k] = getv(trans, k * 7 + j, isbf);
    float R = (act && (lane / 7) == j) ? 0.f : -1e30f;
    int s0 = 1 + c * 64;
    int s1 = s0 + 64; if (s1 > S_LEN) s1 = S_LEN;
    for (int t = s0; t < s1; ++t) {
        float fj = feats[t * NTAG + j];
        float r[7];
        #pragma unroll
        for (int k = 0; k < 7; ++k) r[k] = __shfl(R, i * 7 + k) + tc[k];
        float m = r[0];
        #pragma unroll
        for (int k = 1; k < 7; ++k) m = fmaxf(m, r[k]);
        float sum = 0.f;
        #pragma unroll
        for (int k = 0; k < 7; ++k) sum += __expf(r[k] - m);
        R = m + __logf(sum) + fj;
    }
    if (act) cmats[c * 49 + lane] = R;
}

__global__ void crf_final(const void* start_t, const void* end_t,
                          const float* __restrict__ feats,
                          const float* __restrict__ cmats,
                          void* __restrict__ out) {
    const int isbf = g_isbf16;
    const int lane = threadIdx.x;
    const int j = (lane < 7) ? lane : 0;
    float alpha = (lane < 7) ? (getv(start_t, lane, isbf) + feats[lane]) : -1e30f;
    for (int c = 0; c < NCHUNK; ++c) {
        float r[7];
        #pragma unroll
        for (int i = 0; i < 7; ++i)
            r[i] = __shfl(alpha, i) + cmats[c * 49 + i * 7 + j];
        float m = r[0];
        #pragma unroll
        for (int i = 1; i < 7; ++i) m = fmaxf(m, r[i]);
        float sum = 0.f;
        #pragma unroll
        for (int i = 0; i < 7; ++i) sum += __expf(r[i] - m);
        float na = m + __logf(sum);
        alpha = (lane < 7) ? na : -1e30f;
    }
    float v = (lane < 7) ? (alpha + getv(end_t, lane, isbf)) : -1e30f;
    float m = v;
    #pragma unroll
    for (int d = 1; d < 8; d <<= 1) m = fmaxf(m, __shfl_xor(m, d));
    float s = __expf(v - m);
    #pragma unroll
    for (int d = 1; d < 8; d <<= 1) s += __shfl_xor(s, d);
    if (lane == 0) {
        float r = m + __logf(s);
        if (isbf) ((u16*)out)[0] = f2bf(r);
        else      ((float*)out)[0] = r;
    }
}

// ---------------------------------------------------------------------------
extern "C" void kernel_launch(void* const* d_in, const int* in_sizes, int n_in,
                              void* d_out, int out_size, void* d_ws, size_t ws_size,
                              hipStream_t stream) {
    const void* sentence = d_in[0];      // (8192, 1, 100)
    const void* w_ih_f   = d_in[1];      // (3072, 100)
    const void* w_hh_f   = d_in[2];      // (3072, 768)
    const void* b_ih_f   = d_in[3];
    const void* b_hh_f   = d_in[4];
    const void* w_ih_b   = d_in[5];
    const void* w_hh_b   = d_in[6];
    const void* b_ih_b   = d_in[7];
    const void* b_hh_b   = d_in[8];
    const void* h0       = d_in[9];      // (2,1,768)
    const void* c0       = d_in[10];
    const void* w_tag    = d_in[11];     // (7, 1536)
    const void* b_tag    = d_in[12];
    const void* trans    = d_in[13];
    const void* start_t  = d_in[14];
    const void* end_t    = d_in[15];
    (void)in_sizes; (void)n_in; (void)out_size; (void)ws_size;

    // ---- d_ws scratch: 25.5 MB, fully rewritten each call ----
    char* ws = (char*)d_ws;
    size_t o = 0;
    auto take = [&](size_t bytes) -> char* {
        char* p = ws + o;
        o += (bytes + 255) & ~(size_t)255;
        return p;
    };
    u16*   hfseq  = (u16*)take((size_t)(S_LEN + 1) * H_DIM * 2);
    u16*   hbseq  = (u16*)take((size_t)(S_LEN + 1) * H_DIM * 2);
    float* cstate = (float*)take((size_t)2 * H_DIM * 4);
    float* biasv  = (float*)take((size_t)2 * G4 * 4);
    float* featsb = (float*)take((size_t)S_LEN * NTAG * 4);
    float* cmats  = (float*)take((size_t)NCHUNK * 49 * 4);
    unsigned* flags = (unsigned*)take((size_t)256 * 4);
    int* bail     = (int*)take((size_t)256 * 4);   // bail latch in word 0 (zeroed via flags? no:)
    // note: prep zeroes flags[0..255]; bail shares the next region — zero it too
    // (prep writes flags[i] for i<256; we pass bail as flags+? keep separate & zero in prep)

    detect<<<1, 128, 0, stream>>>(sentence);
    // prep zeroes flags AND bail (bail = flags region trick avoided; do both):
    prep<<<12, 256, 0, stream>>>(b_ih_f, b_hh_f, b_ih_b, b_hh_b, h0, c0,
                                 hfseq, hbseq, cstate, biasv, flags);
    // zero the bail word with a tiny kernel-free trick: reuse prep's flag loop
    // is not possible; use hipMemsetAsync (stream-ordered, capture-legal):
    (void)hipMemsetAsync(bail, 0, 4, stream);

    lstm_persist<<<2 * NBLK, 256, 0, stream>>>(sentence,
                                               w_ih_f, w_hh_f, w_ih_b, w_hh_b,
                                               hfseq, hbseq, cstate, biasv,
                                               flags, bail);

    feats_kernel<<<S_LEN / 4, 256, 0, stream>>>(hfseq, hbseq, w_tag, b_tag, featsb);
    crf_chunks<<<NCHUNK, 64, 0, stream>>>(trans, featsb, cmats);
    crf_final<<<1, 64, 0, stream>>>(start_t, end_t, featsb, cmats, d_out);
}

// Round 14
// 21220.497 us; speedup vs baseline: 2.3479x; 2.3479x over previous
//
#include <hip/hip_runtime.h>
#include <stdint.h>

#define S_LEN 8192
#define E_DIM 100
#define H_DIM 768
#define NTAG 7
#define G4 3072            // 4*H
#define NBLK 96            // blocks per direction
#define NCHUNK 128
#define POLL_LIMIT 150000

typedef unsigned short u16;
typedef __attribute__((ext_vector_type(4))) float f4v;

// input dtype flag (written by detect every call)
__device__ int g_isbf16;

__device__ __forceinline__ u16 f2bf(float f) {
    union { float f; unsigned u; } v; v.f = f;
    unsigned b = v.u;
    unsigned r = (b + 0x7FFFu + ((b >> 16) & 1u)) >> 16;   // RN
    return (u16)r;
}
__device__ __forceinline__ float bf2f(u16 u) {
    union { unsigned u; float f; } v; v.u = ((unsigned)u) << 16;
    return v.f;
}
__device__ __forceinline__ float getv(const void* p, size_t i, int isbf) {
    return isbf ? bf2f(((const u16*)p)[i]) : ((const float*)p)[i];
}
__device__ __forceinline__ float sigm(float x) { return 1.0f / (1.0f + __expf(-x)); }

// ---------------------------------------------------------------------------
// Dtype probe (256 B read, safe under either dtype).
// ---------------------------------------------------------------------------
__global__ void detect(const void* x) {
    __shared__ int cnt;
    if (threadIdx.x == 0) cnt = 0;
    __syncthreads();
    unsigned v = ((const u16*)x)[2 * threadIdx.x];
    int e = (v >> 7) & 0xFF;
    if (e >= 110 && e <= 132) atomicAdd(&cnt, 1);
    __syncthreads();
    if (threadIdx.x == 0) g_isbf16 = (cnt >= 100) ? 1 : 0;
}

// ---------------------------------------------------------------------------
// Prep: zero flags, fold biases, seed h row 0 (bf16) + c0 (fp32).
// (Kernel-boundary writeback makes these LLC-visible before lstm starts.)
// ---------------------------------------------------------------------------
__global__ void prep(const void* bihf, const void* bhhf,
                     const void* bihb, const void* bhhb,
                     const void* h0, const void* c0,
                     u16* __restrict__ hf, u16* __restrict__ hb,
                     float* __restrict__ cst, float* __restrict__ bias,
                     unsigned* __restrict__ flags) {
    const int isbf = g_isbf16;
    int i = blockIdx.x * blockDim.x + threadIdx.x;   // 0..3071
    if (i < 256) flags[i] = 0;
    if (i < G4) {
        bias[i]      = getv(bihf, i, isbf) + getv(bhhf, i, isbf);
        bias[G4 + i] = getv(bihb, i, isbf) + getv(bhhb, i, isbf);
    }
    if (i < H_DIM) {
        hf[i] = f2bf(getv(h0, i, isbf));
        hb[i] = f2bf(getv(h0, H_DIM + i, isbf));
    }
    if (i < 2 * H_DIM) cst[i] = getv(c0, i, isbf);
}

// ---------------------------------------------------------------------------
// Persistent bidirectional LSTM. 192 blocks (96/dir, co-resident), 256 thr:
// 32 gate rows x 8 col-segments. 96 W_hh + 13 W_ih fp32 weights per thread
// in REGISTERS. Cross-block h exchange via RELAXED AGENT-SCOPE ATOMIC dword
// ops (2 bf16 packed / dword): stores write through to the coherent point,
// loads always read it -> NO acquire fence / buffer_inv / wbl2. Release
// ordering: atomic h stores -> __syncthreads (drains vmcnt per wave) ->
// relaxed flag store. Bounded poll + bail latch: always terminates.
// ---------------------------------------------------------------------------
__global__ __launch_bounds__(256, 1) void lstm_persist(
        const void* x,
        const void* wihf, const void* whhf,
        const void* wihb, const void* whhb,
        u16* __restrict__ hfseq, u16* __restrict__ hbseq,
        float* __restrict__ cstate, const float* __restrict__ biasv,
        unsigned* __restrict__ flags, int* __restrict__ bail) {
    const int isbf = g_isbf16;
    const int bid = blockIdx.x;
    const int dir = (bid >= NBLK) ? 1 : 0;
    const int blk = bid - dir * NBLK;
    const int tid = threadIdx.x;
    const int wave = tid >> 6, lane = tid & 63;
    const int seg = tid & 7;            // col segment
    const int row = tid >> 3;           // 0..31 local gate rows
    const int gamma = row & 3;          // gate: 0=i 1=f 2=g 3=o
    const int uloc = row >> 2;          // 0..7
    const int u = blk * 8 + uloc;
    const size_t grow = (size_t)(gamma * H_DIM + u);       // row in (3072, .)
    u16* hseq = dir ? hbseq : hfseq;
    unsigned* myflags = flags + dir * 128;
    const void* Wih = dir ? wihb : wihf;
    const void* Whh = dir ? whhb : whhf;

    __shared__ float sh[800];           // h_t fp32, layout (k/96)*100 + k%96

    // ---- preload weights into registers (one-time) ----
    float whh[96], wih[13];
    if (isbf) {
        const unsigned* p = (const unsigned*)((const u16*)Whh + grow * H_DIM + seg * 96);
        #pragma unroll
        for (int i = 0; i < 48; ++i) {
            unsigned q = p[i];
            whh[2 * i] = bf2f((u16)q); whh[2 * i + 1] = bf2f((u16)(q >> 16));
        }
        const unsigned* px = (const unsigned*)((const u16*)Wih + grow * E_DIM + seg * 12);
        #pragma unroll
        for (int i = 0; i < 6; ++i) {
            unsigned q = px[i];
            wih[2 * i] = bf2f((u16)q); wih[2 * i + 1] = bf2f((u16)(q >> 16));
        }
        wih[12] = (seg < 4) ? bf2f(((const u16*)Wih)[grow * E_DIM + 96 + seg]) : 0.f;
    } else {
        const float* p = (const float*)Whh + grow * H_DIM + seg * 96;
        #pragma unroll
        for (int i = 0; i < 96; ++i) whh[i] = p[i];
        const float* px = (const float*)Wih + grow * E_DIM + seg * 12;
        #pragma unroll
        for (int i = 0; i < 12; ++i) wih[i] = px[i];
        wih[12] = (seg < 4) ? ((const float*)Wih)[grow * E_DIM + 96 + seg] : 0.f;
    }
    const float bias_r = biasv[dir * G4 + grow];
    const int uhalf = blk * 8 + wave * 2 + (lane >> 5);    // unit of this half-wave
    float cst = cstate[dir * H_DIM + uhalf];

    for (int t = 0; t < S_LEN; ++t) {
        const int sx = dir ? (S_LEN - 1 - t) : t;

        // ---- x-projection (pre-wait; x stays L1-warm: no invalidates) ----
        float ax = 0.f;
        if (isbf) {
            const unsigned* xr = (const unsigned*)((const u16*)x + (size_t)sx * E_DIM + seg * 12);
            #pragma unroll
            for (int i = 0; i < 6; ++i) {
                unsigned q = xr[i];
                ax += wih[2 * i] * bf2f((u16)q) + wih[2 * i + 1] * bf2f((u16)(q >> 16));
            }
            if (seg < 4) ax += wih[12] * bf2f(((const u16*)x)[(size_t)sx * E_DIM + 96 + seg]);
        } else {
            const float* xr = (const float*)x + (size_t)sx * E_DIM + seg * 12;
            #pragma unroll
            for (int i = 0; i < 12; ++i) ax += wih[i] * xr[i];
            if (seg < 4) ax += wih[12] * ((const float*)x)[(size_t)sx * E_DIM + 96 + seg];
        }

        // ---- wait for h_t published by all 96 blocks of this direction ----
        if (t > 0) {
            if (wave == 0) {
                if (!__hip_atomic_load(bail, __ATOMIC_RELAXED, __HIP_MEMORY_SCOPE_AGENT)) {
                    const unsigned tgt = (unsigned)t;
                    int polls = 0;
                    for (;;) {
                        unsigned v0 = __hip_atomic_load(&myflags[lane], __ATOMIC_RELAXED,
                                                        __HIP_MEMORY_SCOPE_AGENT);
                        unsigned v1 = (lane < 32)
                            ? __hip_atomic_load(&myflags[64 + lane], __ATOMIC_RELAXED,
                                                __HIP_MEMORY_SCOPE_AGENT) : tgt;
                        if (__all((v0 >= tgt) && (v1 >= tgt))) break;
                        if (__hip_atomic_load(bail, __ATOMIC_RELAXED,
                                              __HIP_MEMORY_SCOPE_AGENT)) break;
                        if (++polls > POLL_LIMIT) {
                            if (lane == 0)
                                __hip_atomic_store(bail, 1, __ATOMIC_RELAXED,
                                                   __HIP_MEMORY_SCOPE_AGENT);
                            break;
                        }
                        __builtin_amdgcn_s_sleep(1);
                    }
                }
                // NO acquire fence: h reads below are agent atomic loads
            }
            __syncthreads();                             // bar A
        }

        // ---- stage h_t -> LDS fp32 via coherent atomic dword loads ----
        {
            const unsigned* hrow32 = (const unsigned*)(hseq + (size_t)t * H_DIM);
            #pragma unroll
            for (int r2 = 0; r2 < 2; ++r2) {
                int d = tid + 256 * r2;                  // dword index 0..383
                if (d < 384) {
                    unsigned p = __hip_atomic_load(&hrow32[d], __ATOMIC_RELAXED,
                                                   __HIP_MEMORY_SCOPE_AGENT);
                    int k = 2 * d;
                    sh[(k / 96) * 100 + (k % 96)] = bf2f((u16)p);
                    ++k;
                    sh[(k / 96) * 100 + (k % 96)] = bf2f((u16)(p >> 16));
                }
            }
        }
        __syncthreads();                                 // bar B

        // ---- h-projection: 96 FMA from LDS ----
        const float* hs = sh + seg * 100;
        float a0 = 0.f, a1 = 0.f, a2 = 0.f, a3 = 0.f;
        #pragma unroll
        for (int i = 0; i < 24; ++i) {
            f4v hv = *(const f4v*)(hs + 4 * i);
            a0 += whh[4 * i]     * hv.x;
            a1 += whh[4 * i + 1] * hv.y;
            a2 += whh[4 * i + 2] * hv.z;
            a3 += whh[4 * i + 3] * hv.w;
        }
        float acc = ax + (a0 + a1) + (a2 + a3);
        acc += __shfl_xor(acc, 1);
        acc += __shfl_xor(acc, 2);
        acc += __shfl_xor(acc, 4);       // 8-lane row sum
        float g = acc + bias_r;

        const int base = lane & 32;      // 4 gates of this half-wave's unit
        float gi = __shfl(g, base + 0);
        float gf = __shfl(g, base + 8);
        float gg = __shfl(g, base + 16);
        float go = __shfl(g, base + 24);
        float ii = sigm(gi), ff = sigm(gf), gt = tanhf(gg), oo = sigm(go);
        float c = ff * cst + ii * gt;
        cst = c;
        float h = oo * tanhf(c);

        // ---- publish h: pack 2 units/dword, atomic store to coherent point ----
        {
            float hodd = __shfl(h, 32);                  // lane0 <- lane32's unit
            if (lane == 0) {
                unsigned pk = (unsigned)f2bf(h) | ((unsigned)f2bf(hodd) << 16);
                unsigned* dst = (unsigned*)(hseq + (size_t)(t + 1) * H_DIM);
                __hip_atomic_store(&dst[blk * 4 + wave], pk, __ATOMIC_RELAXED,
                                   __HIP_MEMORY_SCOPE_AGENT);
            }
        }

        __syncthreads();   // bar C: each wave drains vmcnt before barrier ->
                           // all 4 atomic h-stores are at the coherent point
        if (tid == 0)
            __hip_atomic_store(&myflags[blk], (unsigned)(t + 1), __ATOMIC_RELAXED,
                               __HIP_MEMORY_SCOPE_AGENT);
    }
}

// ---------------------------------------------------------------------------
// feats[s][j] = [hf[s], hb[s]] . w_tag[j] + b_tag[j]; one wave per s.
// ---------------------------------------------------------------------------
__global__ __launch_bounds__(256) void feats_kernel(const u16* __restrict__ hfseq,
                                                    const u16* __restrict__ hbseq,
                                                    const void* w_tag, const void* b_tag,
                                                    float* __restrict__ feats) {
    const int isbf = g_isbf16;
    const int wave = threadIdx.x >> 6, lane = threadIdx.x & 63;
    const int s = blockIdx.x * 4 + wave;
    if (s >= S_LEN) return;
    const u16* hf = hfseq + (size_t)(s + 1) * H_DIM;
    const u16* hb = hbseq + (size_t)(S_LEN - s) * H_DIM;
    float hv[12], hbv[12];
    #pragma unroll
    for (int i = 0; i < 12; ++i) {
        hv[i]  = bf2f(hf[lane + 64 * i]);
        hbv[i] = bf2f(hb[lane + 64 * i]);
    }
    float myf = 0.f;
    for (int j = 0; j < NTAG; ++j) {
        const size_t wr = (size_t)j * (2 * H_DIM);
        float d = 0.f;
        #pragma unroll
        for (int i = 0; i < 12; ++i)
            d += hv[i] * getv(w_tag, wr + lane + 64 * i, isbf)
               + hbv[i] * getv(w_tag, wr + H_DIM + lane + 64 * i, isbf);
        #pragma unroll
        for (int m = 1; m < 64; m <<= 1) d += __shfl_xor(d, m);
        if (lane == j) myf = d + getv(b_tag, j, isbf);
    }
    if (lane < NTAG) feats[(size_t)s * NTAG + lane] = myf;
}

// ---------------------------------------------------------------------------
// CRF parallel scan (log-semiring 7x7 product is associative).
// ---------------------------------------------------------------------------
__global__ void crf_chunks(const void* trans,
                           const float* __restrict__ feats,
                           float* __restrict__ cmats) {
    const int isbf = g_isbf16;
    const int c = blockIdx.x;
    const int lane = threadIdx.x;
    const bool act = lane < 49;
    const int i = act ? (lane / 7) : 0;
    const int j = lane % 7;
    float tc[7];
    #pragma unroll
    for (int k = 0; k < 7; ++k) tc[k] = getv(trans, k * 7 + j, isbf);
    float R = (act && (lane / 7) == j) ? 0.f : -1e30f;
    int s0 = 1 + c * 64;
    int s1 = s0 + 64; if (s1 > S_LEN) s1 = S_LEN;
    for (int t = s0; t < s1; ++t) {
        float fj = feats[t * NTAG + j];
        float r[7];
        #pragma unroll
        for (int k = 0; k < 7; ++k) r[k] = __shfl(R, i * 7 + k) + tc[k];
        float m = r[0];
        #pragma unroll
        for (int k = 1; k < 7; ++k) m = fmaxf(m, r[k]);
        float sum = 0.f;
        #pragma unroll
        for (int k = 0; k < 7; ++k) sum += __expf(r[k] - m);
        R = m + __logf(sum) + fj;
    }
    if (act) cmats[c * 49 + lane] = R;
}

__global__ void crf_final(const void* start_t, const void* end_t,
                          const float* __restrict__ feats,
                          const float* __restrict__ cmats,
                          void* __restrict__ out) {
    const int isbf = g_isbf16;
    const int lane = threadIdx.x;
    const int j = (lane < 7) ? lane : 0;
    float alpha = (lane < 7) ? (getv(start_t, lane, isbf) + feats[lane]) : -1e30f;
    for (int c = 0; c < NCHUNK; ++c) {
        float r[7];
        #pragma unroll
        for (int i = 0; i < 7; ++i)
            r[i] = __shfl(alpha, i) + cmats[c * 49 + i * 7 + j];
        float m = r[0];
        #pragma unroll
        for (int i = 1; i < 7; ++i) m = fmaxf(m, r[i]);
        float sum = 0.f;
        #pragma unroll
        for (int i = 0; i < 7; ++i) sum += __expf(r[i] - m);
        float na = m + __logf(sum);
        alpha = (lane < 7) ? na : -1e30f;
    }
    float v = (lane < 7) ? (alpha + getv(end_t, lane, isbf)) : -1e30f;
    float m = v;
    #pragma unroll
    for (int d = 1; d < 8; d <<= 1) m = fmaxf(m, __shfl_xor(m, d));
    float s = __expf(v - m);
    #pragma unroll
    for (int d = 1; d < 8; d <<= 1) s += __shfl_xor(s, d);
    if (lane == 0) {
        float r = m + __logf(s);
        if (isbf) ((u16*)out)[0] = f2bf(r);
        else      ((float*)out)[0] = r;
    }
}

// ---------------------------------------------------------------------------
extern "C" void kernel_launch(void* const* d_in, const int* in_sizes, int n_in,
                              void* d_out, int out_size, void* d_ws, size_t ws_size,
                              hipStream_t stream) {
    const void* sentence = d_in[0];      // (8192, 1, 100)
    const void* w_ih_f   = d_in[1];      // (3072, 100)
    const void* w_hh_f   = d_in[2];      // (3072, 768)
    const void* b_ih_f   = d_in[3];
    const void* b_hh_f   = d_in[4];
    const void* w_ih_b   = d_in[5];
    const void* w_hh_b   = d_in[6];
    const void* b_ih_b   = d_in[7];
    const void* b_hh_b   = d_in[8];
    const void* h0       = d_in[9];      // (2,1,768)
    const void* c0       = d_in[10];
    const void* w_tag    = d_in[11];     // (7, 1536)
    const void* b_tag    = d_in[12];
    const void* trans    = d_in[13];
    const void* start_t  = d_in[14];
    const void* end_t    = d_in[15];
    (void)in_sizes; (void)n_in; (void)out_size; (void)ws_size;

    // ---- d_ws scratch: 25.5 MB, fully rewritten each call ----
    char* ws = (char*)d_ws;
    size_t o = 0;
    auto take = [&](size_t bytes) -> char* {
        char* p = ws + o;
        o += (bytes + 255) & ~(size_t)255;
        return p;
    };
    u16*   hfseq  = (u16*)take((size_t)(S_LEN + 1) * H_DIM * 2);
    u16*   hbseq  = (u16*)take((size_t)(S_LEN + 1) * H_DIM * 2);
    float* cstate = (float*)take((size_t)2 * H_DIM * 4);
    float* biasv  = (float*)take((size_t)2 * G4 * 4);
    float* featsb = (float*)take((size_t)S_LEN * NTAG * 4);
    float* cmats  = (float*)take((size_t)NCHUNK * 49 * 4);
    unsigned* flags = (unsigned*)take((size_t)256 * 4);
    int* bail     = (int*)take((size_t)256 * 4);

    detect<<<1, 128, 0, stream>>>(sentence);
    prep<<<12, 256, 0, stream>>>(b_ih_f, b_hh_f, b_ih_b, b_hh_b, h0, c0,
                                 hfseq, hbseq, cstate, biasv, flags);
    (void)hipMemsetAsync(bail, 0, 4, stream);

    lstm_persist<<<2 * NBLK, 256, 0, stream>>>(sentence,
                                               w_ih_f, w_hh_f, w_ih_b, w_hh_b,
                                               hfseq, hbseq, cstate, biasv,
                                               flags, bail);

    feats_kernel<<<S_LEN / 4, 256, 0, stream>>>(hfseq, hbseq, w_tag, b_tag, featsb);
    crf_chunks<<<NCHUNK, 64, 0, stream>>>(trans, featsb, cmats);
    crf_final<<<1, 64, 0, stream>>>(start_t, end_t, featsb, cmats, d_out);
}